// Round 3
// baseline (496.361 us; speedup 1.0000x reference)
//
#include <hip/hip_runtime.h>
#include <hip/hip_bf16.h>

// ---------------------------------------------------------------------------
// Swin window MSA, MI355X/gfx950.
// R7: software-pipelined fragment reads with counted lgkmcnt (T4 on the LDS
// side — m201's actual overlap mechanism). Each phase: {barrier; issue NEXT
// phase's ds_reads; stage glds; lgkmcnt(4|8) waits only for THIS phase's
// operands; sched_barrier(0); setprio(1); 16 MFMA}. LDS read service now
// overlaps the MFMA window; barriers 4->2 per K-tile. vmcnt(6) before the
// odd-phase barrier retires tile T+1's staging before its frags are read.
// R6 history: swizzle fix dropped SQ_LDS_BANK_CONFLICT 1.1e7->1.6e6 but dur
// only 142->136us => schedule (not conflicts) is the bottleneck.
// Structure: 256x256 tile, 8 waves (2Mx4N), BK=32, 4-slot LDS ring,
// XCD-bijective swizzle, pre-swizzled global source (g(r)=(r>>1)&3).
// qkv planes: [which][w][h][tok][d]. attn out: head-blocked [h][w][tok][d].
// ---------------------------------------------------------------------------

typedef unsigned short u16;
typedef __bf16 bx8 __attribute__((ext_vector_type(8)));
typedef float f4_t __attribute__((ext_vector_type(4)));

#define QKV_ELEMS 33554432ull        // 1024*16*64*32 per Q/K/V plane
#define SCALE 0.17677669529663687f   // 32^-0.5

static __device__ __forceinline__ u16 f2b(float f) {
    return __builtin_bit_cast(u16, (__bf16)f);
}

typedef const unsigned int __attribute__((address_space(1)))* gas_t;
typedef unsigned int __attribute__((address_space(3)))* las_t;
static __device__ __forceinline__ void glds16(const void* g, void* l) {
    __builtin_amdgcn_global_load_lds((gas_t)g, (las_t)l, 16, 0, 0);
}

// ---- prep: x fp32 -> bf16 (8 elems/thread) --------------------------------
__global__ void cvt_k(const float* __restrict__ X, u16* __restrict__ Xb) {
    size_t i = ((size_t)blockIdx.x * 256 + threadIdx.x) * 8;
    float4 v0 = *(const float4*)(X + i);
    float4 v1 = *(const float4*)(X + i + 4);
    ushort4 p0, p1;
    p0.x = f2b(v0.x); p0.y = f2b(v0.y); p0.z = f2b(v0.z); p0.w = f2b(v0.w);
    p1.x = f2b(v1.x); p1.y = f2b(v1.y); p1.z = f2b(v1.z); p1.w = f2b(v1.w);
    *(ushort4*)(Xb + i) = p0;
    *(ushort4*)(Xb + i + 4) = p1;
}

// ---- prep: W (K x N fp32) -> Wt (N x K bf16) ------------------------------
__global__ void wt_k(const float* __restrict__ W, u16* __restrict__ Wt,
                     int K, int N) {
    int idx = blockIdx.x * 256 + threadIdx.x;
    if (idx >= N * K) return;
    int n = idx / K, k = idx - n * K;
    Wt[idx] = f2b(W[(size_t)k * N + n]);
}

// ---- prep: bias_full[h][q][k] = bias_table[rel_index[q*64+k]][h] ----------
__global__ void bias_k(const float* __restrict__ bias_table,
                       const int* __restrict__ rel_index,
                       float* __restrict__ bias_full) {
    int idx = blockIdx.x * 256 + threadIdx.x;   // 16*4096
    int h = idx >> 12, rc = idx & 4095;
    bias_full[idx] = bias_table[rel_index[rc] * 16 + h];
}

// ---- 256x256-tile pipelined GEMM ------------------------------------------
// C = A @ Bt^T (+bias), K=512 fixed (16 K-tiles of 32).
// MODE 0: A = xb row-major MxK; out -> QKV planes bf16.
// MODE 1: A = attn head-blocked [h][w][tok][32]; out -> fp32 rows (N=512).

#define MF1(av, bv, mt, nt)                                                   \
    acc[mt][nt] = __builtin_amdgcn_mfma_f32_16x16x32_bf16(av, bv,             \
                                                          acc[mt][nt], 0, 0, 0);
#define MF4(av, mt, B)                                                        \
    MF1(av, B[0], mt, 0) MF1(av, B[1], mt, 1)                                 \
    MF1(av, B[2], mt, 2) MF1(av, B[3], mt, 3)

// even phase of tile T: MFMA(aLo x BCUR); prefetch aHi(T) during it.
#define PH_EVEN(T, DOST, BCUR)                                                \
    {                                                                         \
        asm volatile("s_barrier" ::: "memory");                               \
        const char* aT = ldsA + ((T) & 3) * 16384 + wm * 8192 + foff;         \
        aHi[0] = *(const bx8*)(aT + 4096);                                    \
        aHi[1] = *(const bx8*)(aT + 5120);                                    \
        aHi[2] = *(const bx8*)(aT + 6144);                                    \
        aHi[3] = *(const bx8*)(aT + 7168);                                    \
        if (DOST) STAGE_A((T) + 3);                                           \
        asm volatile("s_waitcnt lgkmcnt(4)" ::: "memory");                    \
        __builtin_amdgcn_sched_barrier(0);                                    \
        __builtin_amdgcn_s_setprio(1);                                        \
        MF4(aLo[0], 0, BCUR) MF4(aLo[1], 1, BCUR)                             \
        MF4(aLo[2], 2, BCUR) MF4(aLo[3], 3, BCUR)                             \
        __builtin_amdgcn_s_setprio(0);                                        \
    }

// odd phase of tile T: MFMA(aHi x BCUR); prefetch aLo(T+1), BNXT(T+1).
// VMC: counted vmcnt retiring tile T+1's staging BEFORE its frags are read.
#define PH_ODD(T, DOST, VMC, DORD, BCUR, BNXT)                                \
    {                                                                         \
        if ((VMC) == 6) asm volatile("s_waitcnt vmcnt(6)" ::: "memory");      \
        else if ((VMC) == 4) asm volatile("s_waitcnt vmcnt(4)" ::: "memory"); \
        else if ((VMC) == 0) asm volatile("s_waitcnt vmcnt(0)" ::: "memory"); \
        asm volatile("s_barrier" ::: "memory");                               \
        if (DORD) {                                                           \
            const char* aN = ldsA + (((T) + 1) & 3) * 16384 + wm * 8192 + foff;\
            const char* bN = ldsB + (((T) + 1) & 3) * 16384 + wn * 4096 + foff;\
            BNXT[0] = *(const bx8*)(bN);                                      \
            BNXT[1] = *(const bx8*)(bN + 1024);                               \
            BNXT[2] = *(const bx8*)(bN + 2048);                               \
            BNXT[3] = *(const bx8*)(bN + 3072);                               \
            aLo[0] = *(const bx8*)(aN);                                       \
            aLo[1] = *(const bx8*)(aN + 1024);                                \
            aLo[2] = *(const bx8*)(aN + 2048);                                \
            aLo[3] = *(const bx8*)(aN + 3072);                                \
        }                                                                     \
        if (DOST) STAGE_B((T) + 3);                                           \
        if (DORD) asm volatile("s_waitcnt lgkmcnt(8)" ::: "memory");          \
        else      asm volatile("s_waitcnt lgkmcnt(0)" ::: "memory");          \
        __builtin_amdgcn_sched_barrier(0);                                    \
        __builtin_amdgcn_s_setprio(1);                                        \
        MF4(aHi[0], 4, BCUR) MF4(aHi[1], 5, BCUR)                             \
        MF4(aHi[2], 6, BCUR) MF4(aHi[3], 7, BCUR)                             \
        __builtin_amdgcn_s_setprio(0);                                        \
    }

template <int MODE>
__global__ __launch_bounds__(512, 2) void gemm256_k(
    const u16* __restrict__ A, const u16* __restrict__ Bt,
    const float* __restrict__ bias, void* __restrict__ Out) {
    extern __shared__ __align__(16) char smem[];   // 131072 B dynamic
    const int tid = threadIdx.x;
    const int wave = tid >> 6, lane = tid & 63;
    const int l16 = lane & 15, quad = lane >> 4;
    const int wm = wave >> 2, wn = wave & 3;       // 2M x 4N wave grid

    // T1: bijective XCD swizzle (nwg % 8 == 0), mtile-major per chunk
    const int NT_COL = (MODE == 0) ? 6 : 2;
    const int NWG = (MODE == 0) ? 1536 : 512;
    const int bid = blockIdx.x;
    const int swz = (bid & 7) * (NWG >> 3) + (bid >> 3);
    const int m0 = (swz / NT_COL) << 8;
    const int n0 = (swz % NT_COL) << 8;

    char* const ldsA = smem;            // 4 slots x 16 KB
    char* const ldsB = smem + 65536;    // 4 slots x 16 KB

    // staging: HW lands lane l at base + l*16 -> row 16*wave + (l>>2), chunk l&3.
    // T2: LDS[row][c] = global[row][c ^ g(row&15)], g(r) = (r>>1)&3.
    const int lr = lane >> 2, lc = lane & 3;
    const int swzc = (lc ^ ((lr >> 1) & 3)) * 8;   // elems
    const int stoff = wave * 1024;                 // wave-uniform LDS base

    const u16* Asrc0;
    const u16* Asrc1;
    if (MODE == 0) {
        const int r0 = m0 + wave * 16 + lr;
        Asrc0 = A + (size_t)r0 * 512 + swzc;
        Asrc1 = Asrc0 + (size_t)128 * 512;
    } else {
        const int r0 = m0 + wave * 16 + lr, r1 = r0 + 128;
        Asrc0 = A + (size_t)(r0 >> 6) * 2048 + (r0 & 63) * 32 + swzc;
        Asrc1 = A + (size_t)(r1 >> 6) * 2048 + (r1 & 63) * 32 + swzc;
    }
    const u16* Bsrc0 = Bt + (size_t)(n0 + wave * 16 + lr) * 512 + swzc;
    const u16* Bsrc1 = Bsrc0 + (size_t)128 * 512;

    auto STAGE_A = [&](int T) {
        char* d = ldsA + (T & 3) * 16384 + stoff;
        if (MODE == 0) {
            glds16(Asrc0 + T * 32, d);
            glds16(Asrc1 + T * 32, d + 8192);
        } else {
            glds16(Asrc0 + (size_t)T * 2097152, d);
            glds16(Asrc1 + (size_t)T * 2097152, d + 8192);
        }
    };
    auto STAGE_B = [&](int T) {
        char* d = ldsB + (T & 3) * 16384 + stoff;
        glds16(Bsrc0 + T * 32, d);
        glds16(Bsrc1 + T * 32, d + 8192);
    };

    // frag read: row = block*16 + l16, chunk = quad ^ g(l16)
    const int foff = l16 * 64 + ((quad ^ ((l16 >> 1) & 3)) * 16);

    f4_t acc[8][4];
#pragma unroll
    for (int i = 0; i < 8; ++i)
#pragma unroll
        for (int j = 0; j < 4; ++j) acc[i][j] = (f4_t){0.f, 0.f, 0.f, 0.f};

    bx8 aLo[4], aHi[4], bA[4], bB[4];

    // prologue: stage tiles 0..2 (12 loads); retire tile 0; read its frags
    STAGE_A(0); STAGE_B(0); STAGE_A(1); STAGE_B(1); STAGE_A(2); STAGE_B(2);
    asm volatile("s_waitcnt vmcnt(8)" ::: "memory");
    asm volatile("s_barrier" ::: "memory");
    {
        const char* aT = ldsA + wm * 8192 + foff;
        const char* bT = ldsB + wn * 4096 + foff;
        bA[0] = *(const bx8*)(bT);
        bA[1] = *(const bx8*)(bT + 1024);
        bA[2] = *(const bx8*)(bT + 2048);
        bA[3] = *(const bx8*)(bT + 3072);
        aLo[0] = *(const bx8*)(aT);
        aLo[1] = *(const bx8*)(aT + 1024);
        aLo[2] = *(const bx8*)(aT + 2048);
        aLo[3] = *(const bx8*)(aT + 3072);
    }

    PH_EVEN(0, 1, bA)  PH_ODD(0, 1, 6, 1, bA, bB)
    PH_EVEN(1, 1, bB)  PH_ODD(1, 1, 6, 1, bB, bA)
    PH_EVEN(2, 1, bA)  PH_ODD(2, 1, 6, 1, bA, bB)
    PH_EVEN(3, 1, bB)  PH_ODD(3, 1, 6, 1, bB, bA)
    PH_EVEN(4, 1, bA)  PH_ODD(4, 1, 6, 1, bA, bB)
    PH_EVEN(5, 1, bB)  PH_ODD(5, 1, 6, 1, bB, bA)
    PH_EVEN(6, 1, bA)  PH_ODD(6, 1, 6, 1, bA, bB)
    PH_EVEN(7, 1, bB)  PH_ODD(7, 1, 6, 1, bB, bA)
    PH_EVEN(8, 1, bA)  PH_ODD(8, 1, 6, 1, bA, bB)
    PH_EVEN(9, 1, bB)  PH_ODD(9, 1, 6, 1, bB, bA)
    PH_EVEN(10, 1, bA) PH_ODD(10, 1, 6, 1, bA, bB)
    PH_EVEN(11, 1, bB) PH_ODD(11, 1, 6, 1, bB, bA)
    PH_EVEN(12, 1, bA) PH_ODD(12, 1, 6, 1, bA, bB)
    PH_EVEN(13, 0, bB) PH_ODD(13, 0, 4, 1, bB, bA)
    PH_EVEN(14, 0, bA) PH_ODD(14, 0, 0, 1, bA, bB)
    PH_EVEN(15, 0, bB) PH_ODD(15, 0, -1, 0, bB, bA)

    __syncthreads();   // drain all lgkm + align before LDS reuse in epilogue

    float bv[4];
#pragma unroll
    for (int nt = 0; nt < 4; ++nt) bv[nt] = bias[n0 + wn * 64 + nt * 16 + l16];

    if (MODE == 0) {
        // epilogue: LDS restage -> QKV planes, 1024 B/wave contiguous stores.
        // column layout is [head][which][d]: 96 = 3*32 cols per head.
        u16* c_s = (u16*)smem;          // [128][264] bf16
        u16* qkvp = (u16*)Out;
        const int cg = n0 + wave * 32;
        const int hh = cg / 96;
        const int which = (cg - hh * 96) >> 5;
        u16* plane = qkvp + (size_t)which * QKV_ELEMS + (size_t)hh * 2048;
#pragma unroll
        for (int p = 0; p < 2; ++p) {
            if (wm == p) {
#pragma unroll
                for (int mt = 0; mt < 8; ++mt)
#pragma unroll
                    for (int nt = 0; nt < 4; ++nt)
#pragma unroll
                        for (int i = 0; i < 4; ++i)
                            c_s[(mt * 16 + quad * 4 + i) * 264 +
                                wn * 64 + nt * 16 + l16] =
                                f2b(acc[mt][nt][i] + bv[nt]);
            }
            __syncthreads();
#pragma unroll
            for (int j = 0; j < 8; ++j) {
                int row = j * 16 + (lane >> 2);
                int gm = m0 + p * 128 + row;
                int w_win = gm >> 6, tok = gm & 63;
                uint4 v = *(const uint4*)&c_s[row * 264 + wave * 32 +
                                              (lane & 3) * 8];
                *(uint4*)(plane + (size_t)w_win * 32768 + tok * 32 +
                          (lane & 3) * 8) = v;
            }
            __syncthreads();
        }
    } else {
        // epilogue: fp32 rows, 4 passes of 64 rows, 1024 B/wave stores
        float* c_sf = (float*)smem;     // [64][264] fp32
        float* Of = (float*)Out;
#pragma unroll
        for (int p = 0; p < 4; ++p) {
            if (wm == (p >> 1)) {
                const int mtb = (p & 1) * 4;
#pragma unroll
                for (int mt2 = 0; mt2 < 4; ++mt2)
#pragma unroll
                    for (int nt = 0; nt < 4; ++nt)
#pragma unroll
                        for (int i = 0; i < 4; ++i)
                            c_sf[(mt2 * 16 + quad * 4 + i) * 264 +
                                 wn * 64 + nt * 16 + l16] =
                                acc[mtb + mt2][nt][i] + bv[nt];
            }
            __syncthreads();
#pragma unroll
            for (int j = 0; j < 8; ++j) {
                int flat = tid + 512 * j;           // 64 rows x 64 float4
                int r = flat >> 6, c4 = (flat & 63) * 4;
                float4 v = *(const float4*)&c_sf[r * 264 + c4];
                *(float4*)&Of[(size_t)(m0 + p * 64 + r) * 512 + n0 + c4] = v;
            }
            __syncthreads();
        }
    }
}

// ---- attention: 1 block per (window, head), 4 waves -----------------------
__global__ __launch_bounds__(256) void attn_k(
    const u16* __restrict__ qkv, const float* __restrict__ mask,
    const float* __restrict__ biasf, u16* __restrict__ attn_out) {
    const int bx = blockIdx.x;
    const int w = bx >> 4, h = bx & 15;
    const int wmk = w & 255;  // mask window = b % 256
    const int tid = threadIdx.x;
    const int wave = tid >> 6, lane = tid & 63;
    const int quad = lane >> 4, l16 = lane & 15;

    __shared__ alignas(16) u16 q_s[64 * 40];
    __shared__ alignas(16) u16 k_s[64 * 40];
    __shared__ alignas(16) u16 vT[32 * 72];   // vT[d][tok]
    __shared__ alignas(16) float s_s[64 * 68];
    __shared__ alignas(16) u16 p_s[64 * 72];

    const size_t base = (size_t)((w << 4) + h) * 2048;  // 64*32 per (w,h)
    {
        int tok = tid >> 2, d0 = (tid & 3) * 8;
        uint4 qv = *(const uint4*)(qkv + base + tid * 8);
        *(uint4*)&q_s[tok * 40 + d0] = qv;
        uint4 kv = *(const uint4*)(qkv + QKV_ELEMS + base + tid * 8);
        *(uint4*)&k_s[tok * 40 + d0] = kv;
        uint4 vv = *(const uint4*)(qkv + 2 * QKV_ELEMS + base + tid * 8);
        const u16* pv = (const u16*)&vv;
#pragma unroll
        for (int j = 0; j < 8; ++j) vT[(d0 + j) * 72 + tok] = pv[j];
    }
    __syncthreads();

    // S = Q K^T * scale + bias + mask  (wave -> 16-row strip)
    {
        bx8 a = *(const bx8*)&q_s[(wave * 16 + l16) * 40 + quad * 8];
#pragma unroll
        for (int nt = 0; nt < 4; ++nt) {
            bx8 b = *(const bx8*)&k_s[(nt * 16 + l16) * 40 + quad * 8];
            f4_t acc = (f4_t){0.f, 0.f, 0.f, 0.f};
            acc = __builtin_amdgcn_mfma_f32_16x16x32_bf16(a, b, acc, 0, 0, 0);
#pragma unroll
            for (int i = 0; i < 4; ++i) {
                int r = wave * 16 + quad * 4 + i;
                int c = nt * 16 + l16;
                float s = acc[i] * SCALE + biasf[(h << 12) + (r << 6) + c] +
                          mask[((size_t)wmk * 64 + r) * 64 + c];
                s_s[r * 68 + c] = s;
            }
        }
    }
    __syncthreads();

    // row softmax: 4 threads per row, 16 cols each, shuffle-reduce
    {
        int row = tid >> 2, j = (tid & 3) * 16;
        float mx = -1e30f;
#pragma unroll
        for (int cc = 0; cc < 16; ++cc) mx = fmaxf(mx, s_s[row * 68 + j + cc]);
        mx = fmaxf(mx, __shfl_xor(mx, 1));
        mx = fmaxf(mx, __shfl_xor(mx, 2));
        float e[16], sum = 0.f;
#pragma unroll
        for (int cc = 0; cc < 16; ++cc) {
            e[cc] = __expf(s_s[row * 68 + j + cc] - mx);
            sum += e[cc];
        }
        sum += __shfl_xor(sum, 1);
        sum += __shfl_xor(sum, 2);
        float inv = 1.f / sum;
#pragma unroll
        for (int cc = 0; cc < 16; ++cc) p_s[row * 72 + j + cc] = f2b(e[cc] * inv);
    }
    __syncthreads();   // also fences s_s reads; s_s reused as O stage below

    // O = P V ; restage -> head-blocked [h][w][tok][d], coalesced uint4
    {
        u16* os = (u16*)s_s;   // [64][40]
#pragma unroll
        for (int nt = 0; nt < 2; ++nt) {
            f4_t acc = (f4_t){0.f, 0.f, 0.f, 0.f};
#pragma unroll
            for (int ks = 0; ks < 2; ++ks) {
                bx8 a = *(const bx8*)&p_s[(wave * 16 + l16) * 72 + ks * 32 + quad * 8];
                bx8 b = *(const bx8*)&vT[(nt * 16 + l16) * 72 + ks * 32 + quad * 8];
                acc = __builtin_amdgcn_mfma_f32_16x16x32_bf16(a, b, acc, 0, 0, 0);
            }
#pragma unroll
            for (int i = 0; i < 4; ++i)
                os[(wave * 16 + quad * 4 + i) * 40 + nt * 16 + l16] =
                    f2b(acc[i]);
        }
        __syncthreads();
        int tok = tid >> 2, d8 = (tid & 3) * 8;
        uint4 v = *(const uint4*)&os[tok * 40 + d8];
        *(uint4*)(attn_out + ((((size_t)h << 10) + w) << 11) + tid * 8) = v;
    }
}

extern "C" void kernel_launch(void* const* d_in, const int* in_sizes, int n_in,
                              void* d_out, int out_size, void* d_ws,
                              size_t ws_size, hipStream_t stream) {
    const float* x      = (const float*)d_in[0];
    const float* mask   = (const float*)d_in[1];
    const float* qkv_w  = (const float*)d_in[2];
    const float* qkv_b  = (const float*)d_in[3];
    const float* proj_w = (const float*)d_in[4];
    const float* proj_b = (const float*)d_in[5];
    const float* bias_t = (const float*)d_in[6];
    const int*   rel    = (const int*)d_in[7];
    float* out = (float*)d_out;

    char* ws = (char*)d_ws;
    u16* Wt1 = (u16*)ws;      ws += (size_t)1536 * 512 * 2;   // qkv_w^T bf16
    u16* Wt2 = (u16*)ws;      ws += (size_t)512 * 512 * 2;    // proj_w^T bf16
    float* biasf = (float*)ws; ws += (size_t)16 * 64 * 64 * 4; // bias_full
    u16* qkv = (u16*)ws;      ws += 3 * QKV_ELEMS * 2;        // Q,K,V planes
    u16* attn = (u16*)ws;     ws += QKV_ELEMS * 2;            // attn out bf16
    u16* xb = attn;  // alias: x_bf16 used only before attn_out is written

    cvt_k<<<16384, 256, 0, stream>>>(x, xb);   // 65536*512 / (256*8)
    wt_k<<<3072, 256, 0, stream>>>(qkv_w, Wt1, 512, 1536);
    wt_k<<<1024, 256, 0, stream>>>(proj_w, Wt2, 512, 512);
    bias_k<<<256, 256, 0, stream>>>(bias_t, rel, biasf);
    // QKV projection: M=65536, N=1536, K=512 (256x256 tiles, 6x256 grid)
    gemm256_k<0><<<1536, 512, 131072, stream>>>(xb, Wt1, qkv_b, qkv);
    // window attention: 1024 windows x 16 heads
    attn_k<<<16384, 256, 0, stream>>>(qkv, mask, biasf, attn);
    // output projection: M=65536, N=512, K=512 (2x256 grid)
    gemm256_k<1><<<512, 512, 131072, stream>>>(attn, Wt2, proj_b, out);
}

// Round 4
// 484.857 us; speedup vs baseline: 1.0237x; 1.0237x over previous
//
#include <hip/hip_runtime.h>
#include <hip/hip_bf16.h>

// ---------------------------------------------------------------------------
// Swin window MSA, MI355X/gfx950.
// R8: (a) attn LDS diet: s_s [64][68]->[64][65] f32 (scalar access only, no
// 16B-align need) => 41.5->39.75 KB => 4 blocks/CU (was 3), +33% TLP for the
// latency-bound attention; __launch_bounds__(256,4) guards the VGPR side.
// (b) prep fusion: cvt_k + wt_k(x2) + bias_k -> one prep_k dispatch (block-
// range branch), 7 launches -> 4.
// GEMM loop unchanged from R7 (pipelined counted-lgkm; gemm0 130us/33%
// MfmaUtil — at its structural register-bound ceiling: 128 AGPR acc + 64
// VGPR operand dbuf + addressing ~= the full 256/wave budget @2 waves/SIMD).
// History: R5 256x256 phase sched (175->142), R6 swizzle fix (conflicts
// 1.1e7->1.6e6), R7 pipelined lgkm (136->130).
// qkv planes: [which][w][h][tok][d]. attn out: head-blocked [h][w][tok][d].
// ---------------------------------------------------------------------------

typedef unsigned short u16;
typedef __bf16 bx8 __attribute__((ext_vector_type(8)));
typedef float f4_t __attribute__((ext_vector_type(4)));

#define QKV_ELEMS 33554432ull        // 1024*16*64*32 per Q/K/V plane
#define SCALE 0.17677669529663687f   // 32^-0.5

static __device__ __forceinline__ u16 f2b(float f) {
    return __builtin_bit_cast(u16, (__bf16)f);
}

typedef const unsigned int __attribute__((address_space(1)))* gas_t;
typedef unsigned int __attribute__((address_space(3)))* las_t;
static __device__ __forceinline__ void glds16(const void* g, void* l) {
    __builtin_amdgcn_global_load_lds((gas_t)g, (las_t)l, 16, 0, 0);
}

// ---- fused prep: cvt(x->bf16) + W transposes + bias gather ----------------
// blocks [0,16384): x cvt; [16384,19456): qkv_w^T; [19456,20480): proj_w^T;
// [20480,20736): bias_full[h][q][k] = bias_table[rel_index[q*64+k]][h]
__global__ __launch_bounds__(256) void prep_k(
    const float* __restrict__ X, u16* __restrict__ Xb,
    const float* __restrict__ qkv_w, u16* __restrict__ Wt1,
    const float* __restrict__ proj_w, u16* __restrict__ Wt2,
    const float* __restrict__ bias_t, const int* __restrict__ rel,
    float* __restrict__ biasf) {
    const int b = blockIdx.x;
    if (b < 16384) {
        size_t i = ((size_t)b * 256 + threadIdx.x) * 8;
        float4 v0 = *(const float4*)(X + i);
        float4 v1 = *(const float4*)(X + i + 4);
        ushort4 p0, p1;
        p0.x = f2b(v0.x); p0.y = f2b(v0.y); p0.z = f2b(v0.z); p0.w = f2b(v0.w);
        p1.x = f2b(v1.x); p1.y = f2b(v1.y); p1.z = f2b(v1.z); p1.w = f2b(v1.w);
        *(ushort4*)(Xb + i) = p0;
        *(ushort4*)(Xb + i + 4) = p1;
    } else if (b < 16384 + 3072) {
        int idx = (b - 16384) * 256 + threadIdx.x;   // 1536*512
        int n = idx >> 9, k = idx & 511;
        Wt1[idx] = f2b(qkv_w[(size_t)k * 1536 + n]);
    } else if (b < 16384 + 4096) {
        int idx = (b - 16384 - 3072) * 256 + threadIdx.x;  // 512*512
        int n = idx >> 9, k = idx & 511;
        Wt2[idx] = f2b(proj_w[(size_t)k * 512 + n]);
    } else {
        int idx = (b - 16384 - 4096) * 256 + threadIdx.x;  // 16*4096
        int h = idx >> 12, rc = idx & 4095;
        biasf[idx] = bias_t[rel[rc] * 16 + h];
    }
}

// ---- 256x256-tile pipelined GEMM ------------------------------------------
// C = A @ Bt^T (+bias), K=512 fixed (16 K-tiles of 32).
// MODE 0: A = xb row-major MxK; out -> QKV planes bf16.
// MODE 1: A = attn head-blocked [h][w][tok][32]; out -> fp32 rows (N=512).

#define MF1(av, bv, mt, nt)                                                   \
    acc[mt][nt] = __builtin_amdgcn_mfma_f32_16x16x32_bf16(av, bv,             \
                                                          acc[mt][nt], 0, 0, 0);
#define MF4(av, mt, B)                                                        \
    MF1(av, B[0], mt, 0) MF1(av, B[1], mt, 1)                                 \
    MF1(av, B[2], mt, 2) MF1(av, B[3], mt, 3)

// even phase of tile T: MFMA(aLo x BCUR); prefetch aHi(T) during it.
#define PH_EVEN(T, DOST, BCUR)                                                \
    {                                                                         \
        asm volatile("s_barrier" ::: "memory");                               \
        const char* aT = ldsA + ((T) & 3) * 16384 + wm * 8192 + foff;         \
        aHi[0] = *(const bx8*)(aT + 4096);                                    \
        aHi[1] = *(const bx8*)(aT + 5120);                                    \
        aHi[2] = *(const bx8*)(aT + 6144);                                    \
        aHi[3] = *(const bx8*)(aT + 7168);                                    \
        if (DOST) STAGE_A((T) + 3);                                           \
        asm volatile("s_waitcnt lgkmcnt(4)" ::: "memory");                    \
        __builtin_amdgcn_sched_barrier(0);                                    \
        __builtin_amdgcn_s_setprio(1);                                        \
        MF4(aLo[0], 0, BCUR) MF4(aLo[1], 1, BCUR)                             \
        MF4(aLo[2], 2, BCUR) MF4(aLo[3], 3, BCUR)                             \
        __builtin_amdgcn_s_setprio(0);                                        \
    }

// odd phase of tile T: MFMA(aHi x BCUR); prefetch aLo(T+1), BNXT(T+1).
// VMC: counted vmcnt retiring tile T+1's staging BEFORE its frags are read.
#define PH_ODD(T, DOST, VMC, DORD, BCUR, BNXT)                                \
    {                                                                         \
        if ((VMC) == 6) asm volatile("s_waitcnt vmcnt(6)" ::: "memory");      \
        else if ((VMC) == 4) asm volatile("s_waitcnt vmcnt(4)" ::: "memory"); \
        else if ((VMC) == 0) asm volatile("s_waitcnt vmcnt(0)" ::: "memory"); \
        asm volatile("s_barrier" ::: "memory");                               \
        if (DORD) {                                                           \
            const char* aN = ldsA + (((T) + 1) & 3) * 16384 + wm * 8192 + foff;\
            const char* bN = ldsB + (((T) + 1) & 3) * 16384 + wn * 4096 + foff;\
            BNXT[0] = *(const bx8*)(bN);                                      \
            BNXT[1] = *(const bx8*)(bN + 1024);                               \
            BNXT[2] = *(const bx8*)(bN + 2048);                               \
            BNXT[3] = *(const bx8*)(bN + 3072);                               \
            aLo[0] = *(const bx8*)(aN);                                       \
            aLo[1] = *(const bx8*)(aN + 1024);                                \
            aLo[2] = *(const bx8*)(aN + 2048);                                \
            aLo[3] = *(const bx8*)(aN + 3072);                                \
        }                                                                     \
        if (DOST) STAGE_B((T) + 3);                                           \
        if (DORD) asm volatile("s_waitcnt lgkmcnt(8)" ::: "memory");          \
        else      asm volatile("s_waitcnt lgkmcnt(0)" ::: "memory");          \
        __builtin_amdgcn_sched_barrier(0);                                    \
        __builtin_amdgcn_s_setprio(1);                                        \
        MF4(aHi[0], 4, BCUR) MF4(aHi[1], 5, BCUR)                             \
        MF4(aHi[2], 6, BCUR) MF4(aHi[3], 7, BCUR)                             \
        __builtin_amdgcn_s_setprio(0);                                        \
    }

template <int MODE>
__global__ __launch_bounds__(512, 2) void gemm256_k(
    const u16* __restrict__ A, const u16* __restrict__ Bt,
    const float* __restrict__ bias, void* __restrict__ Out) {
    extern __shared__ __align__(16) char smem[];   // 131072 B dynamic
    const int tid = threadIdx.x;
    const int wave = tid >> 6, lane = tid & 63;
    const int l16 = lane & 15, quad = lane >> 4;
    const int wm = wave >> 2, wn = wave & 3;       // 2M x 4N wave grid

    // T1: bijective XCD swizzle (nwg % 8 == 0), mtile-major per chunk
    const int NT_COL = (MODE == 0) ? 6 : 2;
    const int NWG = (MODE == 0) ? 1536 : 512;
    const int bid = blockIdx.x;
    const int swz = (bid & 7) * (NWG >> 3) + (bid >> 3);
    const int m0 = (swz / NT_COL) << 8;
    const int n0 = (swz % NT_COL) << 8;

    char* const ldsA = smem;            // 4 slots x 16 KB
    char* const ldsB = smem + 65536;    // 4 slots x 16 KB

    // staging: HW lands lane l at base + l*16 -> row 16*wave + (l>>2), chunk l&3.
    // T2: LDS[row][c] = global[row][c ^ g(row&15)], g(r) = (r>>1)&3.
    const int lr = lane >> 2, lc = lane & 3;
    const int swzc = (lc ^ ((lr >> 1) & 3)) * 8;   // elems
    const int stoff = wave * 1024;                 // wave-uniform LDS base

    const u16* Asrc0;
    const u16* Asrc1;
    if (MODE == 0) {
        const int r0 = m0 + wave * 16 + lr;
        Asrc0 = A + (size_t)r0 * 512 + swzc;
        Asrc1 = Asrc0 + (size_t)128 * 512;
    } else {
        const int r0 = m0 + wave * 16 + lr, r1 = r0 + 128;
        Asrc0 = A + (size_t)(r0 >> 6) * 2048 + (r0 & 63) * 32 + swzc;
        Asrc1 = A + (size_t)(r1 >> 6) * 2048 + (r1 & 63) * 32 + swzc;
    }
    const u16* Bsrc0 = Bt + (size_t)(n0 + wave * 16 + lr) * 512 + swzc;
    const u16* Bsrc1 = Bsrc0 + (size_t)128 * 512;

    auto STAGE_A = [&](int T) {
        char* d = ldsA + (T & 3) * 16384 + stoff;
        if (MODE == 0) {
            glds16(Asrc0 + T * 32, d);
            glds16(Asrc1 + T * 32, d + 8192);
        } else {
            glds16(Asrc0 + (size_t)T * 2097152, d);
            glds16(Asrc1 + (size_t)T * 2097152, d + 8192);
        }
    };
    auto STAGE_B = [&](int T) {
        char* d = ldsB + (T & 3) * 16384 + stoff;
        glds16(Bsrc0 + T * 32, d);
        glds16(Bsrc1 + T * 32, d + 8192);
    };

    // frag read: row = block*16 + l16, chunk = quad ^ g(l16)
    const int foff = l16 * 64 + ((quad ^ ((l16 >> 1) & 3)) * 16);

    f4_t acc[8][4];
#pragma unroll
    for (int i = 0; i < 8; ++i)
#pragma unroll
        for (int j = 0; j < 4; ++j) acc[i][j] = (f4_t){0.f, 0.f, 0.f, 0.f};

    bx8 aLo[4], aHi[4], bA[4], bB[4];

    // prologue: stage tiles 0..2 (12 loads); retire tile 0; read its frags
    STAGE_A(0); STAGE_B(0); STAGE_A(1); STAGE_B(1); STAGE_A(2); STAGE_B(2);
    asm volatile("s_waitcnt vmcnt(8)" ::: "memory");
    asm volatile("s_barrier" ::: "memory");
    {
        const char* aT = ldsA + wm * 8192 + foff;
        const char* bT = ldsB + wn * 4096 + foff;
        bA[0] = *(const bx8*)(bT);
        bA[1] = *(const bx8*)(bT + 1024);
        bA[2] = *(const bx8*)(bT + 2048);
        bA[3] = *(const bx8*)(bT + 3072);
        aLo[0] = *(const bx8*)(aT);
        aLo[1] = *(const bx8*)(aT + 1024);
        aLo[2] = *(const bx8*)(aT + 2048);
        aLo[3] = *(const bx8*)(aT + 3072);
    }

    PH_EVEN(0, 1, bA)  PH_ODD(0, 1, 6, 1, bA, bB)
    PH_EVEN(1, 1, bB)  PH_ODD(1, 1, 6, 1, bB, bA)
    PH_EVEN(2, 1, bA)  PH_ODD(2, 1, 6, 1, bA, bB)
    PH_EVEN(3, 1, bB)  PH_ODD(3, 1, 6, 1, bB, bA)
    PH_EVEN(4, 1, bA)  PH_ODD(4, 1, 6, 1, bA, bB)
    PH_EVEN(5, 1, bB)  PH_ODD(5, 1, 6, 1, bB, bA)
    PH_EVEN(6, 1, bA)  PH_ODD(6, 1, 6, 1, bA, bB)
    PH_EVEN(7, 1, bB)  PH_ODD(7, 1, 6, 1, bB, bA)
    PH_EVEN(8, 1, bA)  PH_ODD(8, 1, 6, 1, bA, bB)
    PH_EVEN(9, 1, bB)  PH_ODD(9, 1, 6, 1, bB, bA)
    PH_EVEN(10, 1, bA) PH_ODD(10, 1, 6, 1, bA, bB)
    PH_EVEN(11, 1, bB) PH_ODD(11, 1, 6, 1, bB, bA)
    PH_EVEN(12, 1, bA) PH_ODD(12, 1, 6, 1, bA, bB)
    PH_EVEN(13, 0, bB) PH_ODD(13, 0, 4, 1, bB, bA)
    PH_EVEN(14, 0, bA) PH_ODD(14, 0, 0, 1, bA, bB)
    PH_EVEN(15, 0, bB) PH_ODD(15, 0, -1, 0, bB, bA)

    __syncthreads();   // drain all lgkm + align before LDS reuse in epilogue

    float bv[4];
#pragma unroll
    for (int nt = 0; nt < 4; ++nt) bv[nt] = bias[n0 + wn * 64 + nt * 16 + l16];

    if (MODE == 0) {
        // epilogue: LDS restage -> QKV planes, 1024 B/wave contiguous stores.
        // column layout is [head][which][d]: 96 = 3*32 cols per head.
        u16* c_s = (u16*)smem;          // [128][264] bf16
        u16* qkvp = (u16*)Out;
        const int cg = n0 + wave * 32;
        const int hh = cg / 96;
        const int which = (cg - hh * 96) >> 5;
        u16* plane = qkvp + (size_t)which * QKV_ELEMS + (size_t)hh * 2048;
#pragma unroll
        for (int p = 0; p < 2; ++p) {
            if (wm == p) {
#pragma unroll
                for (int mt = 0; mt < 8; ++mt)
#pragma unroll
                    for (int nt = 0; nt < 4; ++nt)
#pragma unroll
                        for (int i = 0; i < 4; ++i)
                            c_s[(mt * 16 + quad * 4 + i) * 264 +
                                wn * 64 + nt * 16 + l16] =
                                f2b(acc[mt][nt][i] + bv[nt]);
            }
            __syncthreads();
#pragma unroll
            for (int j = 0; j < 8; ++j) {
                int row = j * 16 + (lane >> 2);
                int gm = m0 + p * 128 + row;
                int w_win = gm >> 6, tok = gm & 63;
                uint4 v = *(const uint4*)&c_s[row * 264 + wave * 32 +
                                              (lane & 3) * 8];
                *(uint4*)(plane + (size_t)w_win * 32768 + tok * 32 +
                          (lane & 3) * 8) = v;
            }
            __syncthreads();
        }
    } else {
        // epilogue: fp32 rows, 4 passes of 64 rows, 1024 B/wave stores
        float* c_sf = (float*)smem;     // [64][264] fp32
        float* Of = (float*)Out;
#pragma unroll
        for (int p = 0; p < 4; ++p) {
            if (wm == (p >> 1)) {
                const int mtb = (p & 1) * 4;
#pragma unroll
                for (int mt2 = 0; mt2 < 4; ++mt2)
#pragma unroll
                    for (int nt = 0; nt < 4; ++nt)
#pragma unroll
                        for (int i = 0; i < 4; ++i)
                            c_sf[(mt2 * 16 + quad * 4 + i) * 264 +
                                 wn * 64 + nt * 16 + l16] =
                                acc[mtb + mt2][nt][i] + bv[nt];
            }
            __syncthreads();
#pragma unroll
            for (int j = 0; j < 8; ++j) {
                int flat = tid + 512 * j;           // 64 rows x 64 float4
                int r = flat >> 6, c4 = (flat & 63) * 4;
                float4 v = *(const float4*)&c_sf[r * 264 + c4];
                *(float4*)&Of[(size_t)(m0 + p * 64 + r) * 512 + n0 + c4] = v;
            }
            __syncthreads();
        }
    }
}

// ---- attention: 1 block per (window, head), 4 waves -----------------------
// LDS total 40704 B -> 4 blocks/CU (R8 diet: s_s stride 68->65)
__global__ __launch_bounds__(256, 4) void attn_k(
    const u16* __restrict__ qkv, const float* __restrict__ mask,
    const float* __restrict__ biasf, u16* __restrict__ attn_out) {
    const int bx = blockIdx.x;
    const int w = bx >> 4, h = bx & 15;
    const int wmk = w & 255;  // mask window = b % 256
    const int tid = threadIdx.x;
    const int wave = tid >> 6, lane = tid & 63;
    const int quad = lane >> 4, l16 = lane & 15;

    __shared__ alignas(16) u16 q_s[64 * 40];
    __shared__ alignas(16) u16 k_s[64 * 40];
    __shared__ alignas(16) u16 vT[32 * 72];   // vT[d][tok]
    __shared__ alignas(16) float s_s[64 * 65];
    __shared__ alignas(16) u16 p_s[64 * 72];

    const size_t base = (size_t)((w << 4) + h) * 2048;  // 64*32 per (w,h)
    {
        int tok = tid >> 2, d0 = (tid & 3) * 8;
        uint4 qv = *(const uint4*)(qkv + base + tid * 8);
        *(uint4*)&q_s[tok * 40 + d0] = qv;
        uint4 kv = *(const uint4*)(qkv + QKV_ELEMS + base + tid * 8);
        *(uint4*)&k_s[tok * 40 + d0] = kv;
        uint4 vv = *(const uint4*)(qkv + 2 * QKV_ELEMS + base + tid * 8);
        const u16* pv = (const u16*)&vv;
#pragma unroll
        for (int j = 0; j < 8; ++j) vT[(d0 + j) * 72 + tok] = pv[j];
    }
    __syncthreads();

    // S = Q K^T * scale + bias + mask  (wave -> 16-row strip)
    {
        bx8 a = *(const bx8*)&q_s[(wave * 16 + l16) * 40 + quad * 8];
#pragma unroll
        for (int nt = 0; nt < 4; ++nt) {
            bx8 b = *(const bx8*)&k_s[(nt * 16 + l16) * 40 + quad * 8];
            f4_t acc = (f4_t){0.f, 0.f, 0.f, 0.f};
            acc = __builtin_amdgcn_mfma_f32_16x16x32_bf16(a, b, acc, 0, 0, 0);
#pragma unroll
            for (int i = 0; i < 4; ++i) {
                int r = wave * 16 + quad * 4 + i;
                int c = nt * 16 + l16;
                float s = acc[i] * SCALE + biasf[(h << 12) + (r << 6) + c] +
                          mask[((size_t)wmk * 64 + r) * 64 + c];
                s_s[r * 65 + c] = s;
            }
        }
    }
    __syncthreads();

    // row softmax: 4 threads per row, 16 cols each, shuffle-reduce
    {
        int row = tid >> 2, j = (tid & 3) * 16;
        float mx = -1e30f;
#pragma unroll
        for (int cc = 0; cc < 16; ++cc) mx = fmaxf(mx, s_s[row * 65 + j + cc]);
        mx = fmaxf(mx, __shfl_xor(mx, 1));
        mx = fmaxf(mx, __shfl_xor(mx, 2));
        float e[16], sum = 0.f;
#pragma unroll
        for (int cc = 0; cc < 16; ++cc) {
            e[cc] = __expf(s_s[row * 65 + j + cc] - mx);
            sum += e[cc];
        }
        sum += __shfl_xor(sum, 1);
        sum += __shfl_xor(sum, 2);
        float inv = 1.f / sum;
#pragma unroll
        for (int cc = 0; cc < 16; ++cc) p_s[row * 72 + j + cc] = f2b(e[cc] * inv);
    }
    __syncthreads();   // also fences s_s reads; s_s reused as O stage below

    // O = P V ; restage -> head-blocked [h][w][tok][d], coalesced uint4
    {
        u16* os = (u16*)s_s;   // [64][40]
#pragma unroll
        for (int nt = 0; nt < 2; ++nt) {
            f4_t acc = (f4_t){0.f, 0.f, 0.f, 0.f};
#pragma unroll
            for (int ks = 0; ks < 2; ++ks) {
                bx8 a = *(const bx8*)&p_s[(wave * 16 + l16) * 72 + ks * 32 + quad * 8];
                bx8 b = *(const bx8*)&vT[(nt * 16 + l16) * 72 + ks * 32 + quad * 8];
                acc = __builtin_amdgcn_mfma_f32_16x16x32_bf16(a, b, acc, 0, 0, 0);
            }
#pragma unroll
            for (int i = 0; i < 4; ++i)
                os[(wave * 16 + quad * 4 + i) * 40 + nt * 16 + l16] =
                    f2b(acc[i]);
        }
        __syncthreads();
        int tok = tid >> 2, d8 = (tid & 3) * 8;
        uint4 v = *(const uint4*)&os[tok * 40 + d8];
        *(uint4*)(attn_out + ((((size_t)h << 10) + w) << 11) + tid * 8) = v;
    }
}

extern "C" void kernel_launch(void* const* d_in, const int* in_sizes, int n_in,
                              void* d_out, int out_size, void* d_ws,
                              size_t ws_size, hipStream_t stream) {
    const float* x      = (const float*)d_in[0];
    const float* mask   = (const float*)d_in[1];
    const float* qkv_w  = (const float*)d_in[2];
    const float* qkv_b  = (const float*)d_in[3];
    const float* proj_w = (const float*)d_in[4];
    const float* proj_b = (const float*)d_in[5];
    const float* bias_t = (const float*)d_in[6];
    const int*   rel    = (const int*)d_in[7];
    float* out = (float*)d_out;

    char* ws = (char*)d_ws;
    u16* Wt1 = (u16*)ws;      ws += (size_t)1536 * 512 * 2;   // qkv_w^T bf16
    u16* Wt2 = (u16*)ws;      ws += (size_t)512 * 512 * 2;    // proj_w^T bf16
    float* biasf = (float*)ws; ws += (size_t)16 * 64 * 64 * 4; // bias_full
    u16* qkv = (u16*)ws;      ws += 3 * QKV_ELEMS * 2;        // Q,K,V planes
    u16* attn = (u16*)ws;     ws += QKV_ELEMS * 2;            // attn out bf16
    u16* xb = attn;  // alias: x_bf16 used only before attn_out is written

    // fused prep: cvt + qkv_w^T + proj_w^T + bias (16384+3072+1024+256)
    prep_k<<<20736, 256, 0, stream>>>(x, xb, qkv_w, Wt1, proj_w, Wt2,
                                      bias_t, rel, biasf);
    // QKV projection: M=65536, N=1536, K=512 (256x256 tiles)
    gemm256_k<0><<<1536, 512, 131072, stream>>>(xb, Wt1, qkv_b, qkv);
    // window attention: 1024 windows x 16 heads
    attn_k<<<16384, 256, 0, stream>>>(qkv, mask, biasf, attn);
    // output projection: M=65536, N=512, K=512
    gemm256_k<1><<<512, 512, 131072, stream>>>(attn, Wt2, proj_b, out);
}